// Round 1
// 494.370 us; speedup vs baseline: 1.0838x; 1.0838x over previous
//
#include <hip/hip_runtime.h>
#include <hip/hip_bf16.h>

// Problem constants (from reference)
constexpr int N_NODES = 50000;
constexpr int N_EDGES = 600000;
constexpr int ND = 128;   // NODE_DIM
constexpr int ED = 64;    // EDGE_DIM
constexpr int MD = 128;   // MSG_DIM
constexpr int H1 = 32;    // edge MLP hidden
constexpr int H2 = 64;    // node MLP hidden

typedef __attribute__((ext_vector_type(8))) short short8;   // 8 bf16 (4 VGPRs)
typedef __attribute__((ext_vector_type(4))) float f32x4;    // MFMA acc

#define MFMA16(a, b, c) __builtin_amdgcn_mfma_f32_16x16x32_bf16((a), (b), (c), 0, 0, 0)

// ---------------- workspace layout (bytes) ----------------
constexpr size_t WS_MSGS    = 0;                                        // E*128 bf16
constexpr size_t WS_PRE     = WS_MSGS + (size_t)N_EDGES * MD * 2;       // N*128 bf16 (a1|a2|a3)
constexpr size_t WS_POS     = WS_PRE + (size_t)N_NODES * 128 * 2;       // E int
constexpr size_t WS_COUNTS  = WS_POS + (size_t)N_EDGES * 4;             // N int
constexpr size_t WS_OFFSETS = WS_COUNTS + (size_t)N_NODES * 4;          // N+1 int
constexpr size_t WS_WFE     = ((WS_OFFSETS + (size_t)(N_NODES + 1) * 4 + 15) / 16) * 16;
constexpr size_t WS_WFN     = WS_WFE + (size_t)44 * 64 * 16;            // 44 edge frags
constexpr size_t WS_END     = WS_WFN + (size_t)32 * 64 * 16;            // 32 node frags

__device__ inline float bflo(unsigned u) { return __uint_as_float(u << 16); }
__device__ inline float bfhi(unsigned u) { return __uint_as_float(u & 0xffff0000u); }
__device__ inline float bf2f(unsigned short v) { return __uint_as_float((unsigned)v << 16); }
__device__ inline short f2bf(float f) {
    __hip_bfloat16 h = __float2bfloat16(f);
    return *reinterpret_cast<short*>(&h);
}

// ---------------- weight fragment prep (once, tiny) ----------------
// B-fragment layout for mfma_f32_16x16x32_bf16: lane holds B[k=quad*8+j][n=lane&15],
// j=0..7 contiguous -> one short8 (16B) per (frag, lane).
// wfE frag ids: We1e(edge rows of We1)=0..3 (kt*2+nt), We2=4..11 (nt),
//               Wn1b(msg rows of Wn1)=12..27 (kt*4+nt), Wn2=28..43 (kt*8+nt).
// wfN frag ids: combined 128x128 B = [We1[0:128] | We1[128:256] | Wn1[0:128]] -> kt*8+nt.
__global__ __launch_bounds__(256) void wprep(
    const float* __restrict__ We1, const float* __restrict__ We2,
    const float* __restrict__ Wn1, const float* __restrict__ Wn2,
    short8* __restrict__ wfE, short8* __restrict__ wfN)
{
    const int g = blockIdx.x * 256 + threadIdx.x;   // 0..4863
    const int lane = g & 63;
    const int f = g >> 6;                            // 0..75
    const int m16 = lane & 15, quad = lane >> 4;
    short v[8];
    if (f < 44) {
        #pragma unroll
        for (int j = 0; j < 8; ++j) {
            const int kq = quad * 8 + j;
            float s;
            if (f < 4) {
                const int kt = f >> 1, nt = f & 1;
                s = We1[(size_t)(2 * ND + kt * 32 + kq) * H1 + nt * 16 + m16];
            } else if (f < 12) {
                const int nt = f - 4;
                s = We2[(size_t)kq * MD + nt * 16 + m16];
            } else if (f < 28) {
                const int ff = f - 12, kt = ff >> 2, nt = ff & 3;
                s = Wn1[(size_t)(ND + kt * 32 + kq) * H2 + nt * 16 + m16];
            } else {
                const int ff = f - 28, kt = ff >> 3, nt = ff & 7;
                s = Wn2[(size_t)(kt * 32 + kq) * MD + nt * 16 + m16];
            }
            v[j] = f2bf(s);
        }
        wfE[g] = short8{v[0], v[1], v[2], v[3], v[4], v[5], v[6], v[7]};
    } else {
        const int ff = f - 44, kt = ff >> 3, nt = ff & 7;
        const int n = nt * 16 + m16;
        #pragma unroll
        for (int j = 0; j < 8; ++j) {
            const int k = kt * 32 + quad * 8 + j;
            float s;
            if (n < 32)      s = We1[(size_t)k * H1 + n];
            else if (n < 64) s = We1[(size_t)(ND + k) * H1 + (n - 32)];
            else             s = Wn1[(size_t)k * H2 + (n - 64)];
            v[j] = f2bf(s);
        }
        wfN[(size_t)(f - 44) * 64 + lane] = short8{v[0], v[1], v[2], v[3], v[4], v[5], v[6], v[7]};
    }
}

// ---------------- CSR: histogram + within-segment position -----------------
__global__ __launch_bounds__(256) void hist_pos(const int* __restrict__ eidx,
                                                int* __restrict__ counts,
                                                int* __restrict__ pos) {
    const int e = blockIdx.x * 256 + threadIdx.x;
    if (e < N_EDGES) pos[e] = atomicAdd(&counts[eidx[N_EDGES + e]], 1);
}

__global__ __launch_bounds__(1024) void scan_kernel(const int* __restrict__ counts,
                                                    int* __restrict__ offsets) {
    constexpr int T = 1024;
    constexpr int CHUNK = (N_NODES + T - 1) / T;  // 49
    const int tid = threadIdx.x;
    const int base = tid * CHUNK;
    int s = 0;
    #pragma unroll
    for (int i = 0; i < CHUNK; ++i) {
        const int idx = base + i;
        if (idx < N_NODES) s += counts[idx];
    }
    __shared__ int sm[T];
    sm[tid] = s;
    __syncthreads();
    for (int off = 1; off < T; off <<= 1) {
        const int v = (tid >= off) ? sm[tid - off] : 0;
        __syncthreads();
        sm[tid] += v;
        __syncthreads();
    }
    int run = sm[tid] - s;
    #pragma unroll
    for (int i = 0; i < CHUNK; ++i) {
        const int idx = base + i;
        if (idx < N_NODES) {
            offsets[idx] = run;
            run += counts[idx];
        }
    }
    if (tid == T - 1) offsets[N_NODES] = sm[T - 1];
}

// ---------------- node precompute as MFMA GEMM: pre = nf @ [B128x128] -------
__global__ __launch_bounds__(256) void node_pre_mfma(
    const float* __restrict__ nf, const short8* __restrict__ wfN,
    unsigned short* __restrict__ pre)
{
    __shared__ short ost[4][2048];   // per-wave 16x128 out stage
    const int tid = threadIdx.x;
    const int w = tid >> 6, lane = tid & 63;
    const int m16 = lane & 15, quad = lane >> 4;
    const int n0 = blockIdx.x * 64 + w * 16;

    short8 a[4];
    #pragma unroll
    for (int kt = 0; kt < 4; ++kt) {
        const int node = min(n0 + m16, N_NODES - 1);
        const float* pn = nf + (size_t)node * ND + kt * 32 + quad * 8;
        const float4 f0 = *(const float4*)pn;
        const float4 f1 = *(const float4*)(pn + 4);
        a[kt] = short8{f2bf(f0.x), f2bf(f0.y), f2bf(f0.z), f2bf(f0.w),
                       f2bf(f1.x), f2bf(f1.y), f2bf(f1.z), f2bf(f1.w)};
    }
    f32x4 acc[8];
    #pragma unroll
    for (int nt = 0; nt < 8; ++nt) acc[nt] = f32x4{0.f, 0.f, 0.f, 0.f};
    #pragma unroll
    for (int kt = 0; kt < 4; ++kt) {
        #pragma unroll
        for (int nt = 0; nt < 8; ++nt)
            acc[nt] = MFMA16(a[kt], wfN[(size_t)(kt * 8 + nt) * 64 + lane], acc[nt]);
    }
    short* o = &ost[w][0];
    #pragma unroll
    for (int nt = 0; nt < 8; ++nt)
        #pragma unroll
        for (int r = 0; r < 4; ++r)
            o[(quad * 4 + r) * 128 + nt * 16 + m16] = f2bf(acc[nt][r]);  // no relu
    asm volatile("s_waitcnt lgkmcnt(0)" ::: "memory");
    #pragma unroll
    for (int i = 0; i < 4; ++i) {
        const int row = i * 4 + quad;
        const int node = n0 + row;
        if (node < N_NODES) {
            const uint4 v = ((const uint4*)(o + row * 128))[m16];
            *((uint4*)(pre + (size_t)node * 128) + m16) = v;
        }
    }
}

// ---------------- fused 4-layer edge MLP, full MFMA -------------------------
// 64 edges/block, 4 waves x 16-edge tiles. Waves fully independent (no block
// barrier: gather mapping et=tid>>2 is wave-local). LDS: alb/h2 aliased onto
// l1init (dead after L1 acc-init reads) -> 36.1KB/block -> 4 blocks/CU.
__global__ __launch_bounds__(256, 4) void edge_mfma(
    const float* __restrict__ ef, const int* __restrict__ eidx,
    const unsigned short* __restrict__ pre,
    const int* __restrict__ pos, const int* __restrict__ offsets,
    const short8* __restrict__ wfE,
    const float* __restrict__ be1, const float* __restrict__ be2,
    const float* __restrict__ bn1, const float* __restrict__ bn2,
    unsigned short* __restrict__ msgs)
{
    constexpr int TE = 64;
    // per-wave 2304B window of l1init doubles as alb (stride 40) / h2 (stride 72)
    __shared__ float l1init[TE][36];            // a1[src]+a2[dst]+be1 (fp32, padded)
    __shared__ unsigned short a3lds[TE][72];    // a3[dst] bf16 (padded)
    __shared__ int slotlds[TE];
    __shared__ short wbufB[4][2176];            // msgbuf(stride 136) / outstage(stride 128)

    const int tid = threadIdx.x;
    const int e0 = blockIdx.x * TE;
    const int w = tid >> 6, lane = tid & 63;
    const int m16 = lane & 15, quad = lane >> 4;
    const int er0 = w * 16;

    // ---- front-load ef global loads (latency hides under gather) ----
    float4 efv0, efv1, efv2, efv3;
    {
        const float* pe = ef + (size_t)(e0 + er0 + m16) * ED + quad * 8;
        efv0 = *(const float4*)pe;
        efv1 = *(const float4*)(pe + 4);
        efv2 = *(const float4*)(pe + 32);
        efv3 = *(const float4*)(pe + 36);
    }
    // ---- preload all biases (L1-cached broadcast) ----
    float bias2[8], bias3[4], bias4[8];
    #pragma unroll
    for (int nt = 0; nt < 8; ++nt) bias2[nt] = be2[nt * 16 + m16];
    #pragma unroll
    for (int nt = 0; nt < 4; ++nt) bias3[nt] = bn1[nt * 16 + m16];
    #pragma unroll
    for (int nt = 0; nt < 8; ++nt) bias4[nt] = bn2[nt * 16 + m16];

    // ---- uniform gather: 4 lanes per edge, no divergent branch ----
    {
        const int et = tid >> 2, p = tid & 3;   // wave-local: et in [16w, 16w+16)
        const int e = e0 + et;
        const int src = eidx[e];
        const int dst = eidx[N_EDGES + e];
        const uint4* pa = (const uint4*)(pre + (size_t)src * 128);
        const uint4* pd = (const uint4*)(pre + (size_t)dst * 128);
        const uint4 ua = pa[p];                 // a1 slice
        const uint4 ud = pd[4 + p];             // a2 slice (+32 shorts)
        const uint4 s0 = pd[8 + 2 * p];         // a3 slices (+64 shorts)
        const uint4 s1 = pd[9 + 2 * p];
        const float4 b0 = ((const float4*)be1)[2 * p];
        const float4 b1 = ((const float4*)be1)[2 * p + 1];
        float4 r0, r1;
        r0.x = bflo(ua.x) + bflo(ud.x) + b0.x;
        r0.y = bfhi(ua.x) + bfhi(ud.x) + b0.y;
        r0.z = bflo(ua.y) + bflo(ud.y) + b0.z;
        r0.w = bfhi(ua.y) + bfhi(ud.y) + b0.w;
        r1.x = bflo(ua.z) + bflo(ud.z) + b1.x;
        r1.y = bfhi(ua.z) + bfhi(ud.z) + b1.y;
        r1.z = bflo(ua.w) + bflo(ud.w) + b1.z;
        r1.w = bfhi(ua.w) + bfhi(ud.w) + b1.w;
        float4* o = (float4*)&l1init[et][p * 8];
        o[0] = r0; o[1] = r1;
        uint4* oa = (uint4*)&a3lds[et][p * 16];
        oa[0] = s0; oa[1] = s1;
        const int sl = offsets[dst] + pos[e];
        if (p == 3) slotlds[et] = sl;
    }
    // wave-local LDS handoff (writes all by this wave's lanes)
    asm volatile("s_waitcnt lgkmcnt(0)" ::: "memory");

    short8 aef0 = short8{f2bf(efv0.x), f2bf(efv0.y), f2bf(efv0.z), f2bf(efv0.w),
                         f2bf(efv1.x), f2bf(efv1.y), f2bf(efv1.z), f2bf(efv1.w)};
    short8 aef1 = short8{f2bf(efv2.x), f2bf(efv2.y), f2bf(efv2.z), f2bf(efv2.w),
                         f2bf(efv3.x), f2bf(efv3.y), f2bf(efv3.z), f2bf(efv3.w)};

    short* alb = (short*)&l1init[er0][0];   // ALIAS: 2304B/wave, reused after L1 init
    short* msb = &wbufB[w][0];

    // ---- L1: h(16x32) = relu(l1init + ef @ We1e) ----
    // read ALL acc inits first (alb writes below alias l1init)
    f32x4 acc1[2];
    #pragma unroll
    for (int nt = 0; nt < 2; ++nt)
        #pragma unroll
        for (int r = 0; r < 4; ++r)
            acc1[nt][r] = l1init[er0 + quad * 4 + r][nt * 16 + m16];
    #pragma unroll
    for (int nt = 0; nt < 2; ++nt) {
        acc1[nt] = MFMA16(aef0, wfE[(size_t)(0 * 2 + nt) * 64 + lane], acc1[nt]);
        acc1[nt] = MFMA16(aef1, wfE[(size_t)(1 * 2 + nt) * 64 + lane], acc1[nt]);
    }
    #pragma unroll
    for (int nt = 0; nt < 2; ++nt)
        #pragma unroll
        for (int r = 0; r < 4; ++r)
            alb[(quad * 4 + r) * 40 + nt * 16 + m16] = f2bf(fmaxf(acc1[nt][r], 0.0f));
    asm volatile("s_waitcnt lgkmcnt(0)" ::: "memory");

    // ---- L2: msg(16x128) = relu(h @ We2 + be2) ----
    const short8 ah = *(const short8*)(alb + m16 * 40 + quad * 8);
    f32x4 acc2[8];
    #pragma unroll
    for (int nt = 0; nt < 8; ++nt) {
        acc2[nt] = f32x4{bias2[nt], bias2[nt], bias2[nt], bias2[nt]};
        acc2[nt] = MFMA16(ah, wfE[(size_t)(4 + nt) * 64 + lane], acc2[nt]);
    }
    #pragma unroll
    for (int nt = 0; nt < 8; ++nt)
        #pragma unroll
        for (int r = 0; r < 4; ++r)
            msb[(quad * 4 + r) * 136 + nt * 16 + m16] = f2bf(fmaxf(acc2[nt][r], 0.0f));
    asm volatile("s_waitcnt lgkmcnt(0)" ::: "memory");

    // ---- L3: h2(16x64) = relu(a3 + bn1 + msg @ Wn1b) ----
    short8 am[4];
    #pragma unroll
    for (int kt = 0; kt < 4; ++kt)
        am[kt] = *(const short8*)(msb + m16 * 136 + kt * 32 + quad * 8);
    f32x4 acc3[4];
    #pragma unroll
    for (int nt = 0; nt < 4; ++nt)
        #pragma unroll
        for (int r = 0; r < 4; ++r)
            acc3[nt][r] = bias3[nt] + bf2f(a3lds[er0 + quad * 4 + r][nt * 16 + m16]);
    #pragma unroll
    for (int kt = 0; kt < 4; ++kt) {
        #pragma unroll
        for (int nt = 0; nt < 4; ++nt)
            acc3[nt] = MFMA16(am[kt], wfE[(size_t)(12 + kt * 4 + nt) * 64 + lane], acc3[nt]);
    }
    #pragma unroll
    for (int nt = 0; nt < 4; ++nt)
        #pragma unroll
        for (int r = 0; r < 4; ++r)
            alb[(quad * 4 + r) * 72 + nt * 16 + m16] = f2bf(fmaxf(acc3[nt][r], 0.0f));
    asm volatile("s_waitcnt lgkmcnt(0)" ::: "memory");

    // ---- L4: out(16x128) = relu(h2 @ Wn2 + bn2) ----
    short8 a4[2];
    #pragma unroll
    for (int kt = 0; kt < 2; ++kt)
        a4[kt] = *(const short8*)(alb + m16 * 72 + kt * 32 + quad * 8);
    f32x4 acc4[8];
    #pragma unroll
    for (int nt = 0; nt < 8; ++nt)
        acc4[nt] = f32x4{bias4[nt], bias4[nt], bias4[nt], bias4[nt]};
    #pragma unroll
    for (int kt = 0; kt < 2; ++kt) {
        #pragma unroll
        for (int nt = 0; nt < 8; ++nt)
            acc4[nt] = MFMA16(a4[kt], wfE[(size_t)(28 + kt * 8 + nt) * 64 + lane], acc4[nt]);
    }
    #pragma unroll
    for (int nt = 0; nt < 8; ++nt)
        #pragma unroll
        for (int r = 0; r < 4; ++r)
            msb[(quad * 4 + r) * 128 + nt * 16 + m16] = f2bf(fmaxf(acc4[nt][r], 0.0f));
    asm volatile("s_waitcnt lgkmcnt(0)" ::: "memory");

    // ---- coalesced row store to msgs[slot] (quarter-wave per 256B row) ----
    #pragma unroll
    for (int i = 0; i < 4; ++i) {
        const int row = i * 4 + quad;
        const int sl = slotlds[er0 + row];
        const uint4 v = ((const uint4*)(msb + row * 128))[m16];
        *((uint4*)(msgs + (size_t)sl * 128) + m16) = v;
    }
}

// ---------------- Phase B: per-node streaming sum (msgs CSR-sorted) ---------
// 16 lanes per node, uint4 (16B) loads: 256B/row/iter, 2x unrolled.
__global__ __launch_bounds__(256) void gather2(
    const float* __restrict__ nf,
    const uint4* __restrict__ msgs4,
    const int* __restrict__ offsets,
    float* __restrict__ out)
{
    const int node = blockIdx.x * 16 + (threadIdx.x >> 4);
    const int m16 = threadIdx.x & 15;

    const float4* pn = (const float4*)(nf + (size_t)node * ND) + m16 * 2;
    const float4 n0 = pn[0];
    const float4 n1 = pn[1];

    const int beg = offsets[node];
    const int end = offsets[node + 1];

    float4 s0 = float4{0.f, 0.f, 0.f, 0.f};
    float4 s1 = float4{0.f, 0.f, 0.f, 0.f};
    const uint4* p = msgs4 + (size_t)beg * 16 + m16;   // 16 uint4 per 256B msg row
    int i = beg;
    for (; i + 1 < end; i += 2, p += 32) {
        const uint4 u0 = p[0];
        const uint4 u1 = p[16];
        s0.x += bflo(u0.x); s0.y += bfhi(u0.x);
        s0.z += bflo(u0.y); s0.w += bfhi(u0.y);
        s1.x += bflo(u0.z); s1.y += bfhi(u0.z);
        s1.z += bflo(u0.w); s1.w += bfhi(u0.w);
        s0.x += bflo(u1.x); s0.y += bfhi(u1.x);
        s0.z += bflo(u1.y); s0.w += bfhi(u1.y);
        s1.x += bflo(u1.z); s1.y += bfhi(u1.z);
        s1.z += bflo(u1.w); s1.w += bfhi(u1.w);
    }
    if (i < end) {
        const uint4 u = p[0];
        s0.x += bflo(u.x); s0.y += bfhi(u.x);
        s0.z += bflo(u.y); s0.w += bfhi(u.y);
        s1.x += bflo(u.z); s1.y += bfhi(u.z);
        s1.z += bflo(u.w); s1.w += bfhi(u.w);
    }
    s0.x += n0.x; s0.y += n0.y; s0.z += n0.z; s0.w += n0.w;
    s1.x += n1.x; s1.y += n1.y; s1.z += n1.z; s1.w += n1.w;

    float4* po = (float4*)(out + (size_t)node * ND) + m16 * 2;
    po[0] = s0;
    po[1] = s1;
}

extern "C" void kernel_launch(void* const* d_in, const int* in_sizes, int n_in,
                              void* d_out, int out_size, void* d_ws, size_t ws_size,
                              hipStream_t stream) {
    const float* nf  = (const float*)d_in[0];
    const float* ef  = (const float*)d_in[1];
    const int*  eidx = (const int*)d_in[2];
    const float* We1 = (const float*)d_in[3];
    const float* be1 = (const float*)d_in[4];
    const float* We2 = (const float*)d_in[5];
    const float* be2 = (const float*)d_in[6];
    const float* Wn1 = (const float*)d_in[7];
    const float* bn1 = (const float*)d_in[8];
    const float* Wn2 = (const float*)d_in[9];
    const float* bn2 = (const float*)d_in[10];
    float* out = (float*)d_out;

    char* ws = (char*)d_ws;
    unsigned short* msgs = (unsigned short*)(ws + WS_MSGS);
    unsigned short* pre  = (unsigned short*)(ws + WS_PRE);
    int* pos             = (int*)(ws + WS_POS);
    int* counts          = (int*)(ws + WS_COUNTS);
    int* offsets         = (int*)(ws + WS_OFFSETS);
    short8* wfE          = (short8*)(ws + WS_WFE);
    short8* wfN          = (short8*)(ws + WS_WFN);
    (void)ws_size; (void)WS_END;

    hipMemsetAsync(counts, 0, (size_t)N_NODES * 4, stream);
    wprep<<<19, 256, 0, stream>>>(We1, We2, Wn1, Wn2, wfE, wfN);
    hist_pos<<<(N_EDGES + 255) / 256, 256, 0, stream>>>(eidx, counts, pos);
    scan_kernel<<<1, 1024, 0, stream>>>(counts, offsets);
    node_pre_mfma<<<(N_NODES + 63) / 64, 256, 0, stream>>>(nf, wfN, pre);
    edge_mfma<<<N_EDGES / 64, 256, 0, stream>>>(
        ef, eidx, pre, pos, offsets, wfE, be1, be2, bn1, bn2, msgs);
    gather2<<<N_NODES / 16, 256, 0, stream>>>(nf, (const uint4*)msgs, offsets, out);
}

// Round 2
// 459.154 us; speedup vs baseline: 1.1669x; 1.0767x over previous
//
#include <hip/hip_runtime.h>
#include <hip/hip_bf16.h>

// Problem constants (from reference)
constexpr int N_NODES = 50000;
constexpr int N_EDGES = 600000;
constexpr int ND = 128;   // NODE_DIM
constexpr int ED = 64;    // EDGE_DIM
constexpr int MD = 128;   // MSG_DIM
constexpr int H1 = 32;    // edge MLP hidden
constexpr int H2 = 64;    // node MLP hidden

typedef __attribute__((ext_vector_type(8))) short short8;   // 8 bf16 (4 VGPRs)
typedef __attribute__((ext_vector_type(4))) float f32x4;    // MFMA acc
typedef __attribute__((ext_vector_type(4))) unsigned int uint32x4;

#define MFMA16(a, b, c) __builtin_amdgcn_mfma_f32_16x16x32_bf16((a), (b), (c), 0, 0, 0)

// ---------------- workspace layout (bytes) ----------------
constexpr int COUNTS_PAD = 53248;   // 1024*52 (scan CHUNK=52, int4 loads)
constexpr size_t WS_MSGS    = 0;                                        // E*128 bf16
constexpr size_t WS_PRE     = WS_MSGS + (size_t)N_EDGES * MD * 2;       // N*128 bf16 (a1|a2|a3)
constexpr size_t WS_POS     = WS_PRE + (size_t)N_NODES * 128 * 2;       // E int
constexpr size_t WS_COUNTS  = WS_POS + (size_t)N_EDGES * 4;             // COUNTS_PAD int
constexpr size_t WS_OFFSETS = WS_COUNTS + (size_t)COUNTS_PAD * 4;       // N+1 int
constexpr size_t WS_WFE     = ((WS_OFFSETS + (size_t)(N_NODES + 1) * 4 + 15) / 16) * 16;
constexpr size_t WS_WFN     = WS_WFE + (size_t)44 * 64 * 16;            // 44 edge frags
constexpr size_t WS_END     = WS_WFN + (size_t)32 * 64 * 16;            // 32 node frags

__device__ inline float bflo(unsigned u) { return __uint_as_float(u << 16); }
__device__ inline float bfhi(unsigned u) { return __uint_as_float(u & 0xffff0000u); }
__device__ inline short f2bf(float f) {
    __hip_bfloat16 h = __float2bfloat16(f);
    return *reinterpret_cast<short*>(&h);
}
// packed f32 pair -> bf16 pair (1 instr)
__device__ inline unsigned pkbf(float a, float b) {
    unsigned r;
    asm("v_cvt_pk_bf16_f32 %0, %1, %2" : "=v"(r) : "v"(a), "v"(b));
    return r;
}
__device__ inline unsigned prelu(float a, float b) {
    return pkbf(fmaxf(a, 0.0f), fmaxf(b, 0.0f));
}
__device__ inline short8 pack8(unsigned w0, unsigned w1, unsigned w2, unsigned w3) {
    uint32x4 t{w0, w1, w2, w3};
    return __builtin_bit_cast(short8, t);
}

// Hidden-dim relabeling for swapped-operand layer chaining:
// layer i's output at lane(q,m16) reg (mt,r) carries h = mt*16 + q*4 + r,
// which slots into next layer's B-operand k = kt*32 + q*8 + j with
// mt = kt*2 + (j>>2), r = j&3. Fold h(k) into the weight row order here.
__device__ inline int hperm(int kt, int kq) {   // kq = quad*8+j in [0,32)
    return (kt * 2 + ((kq >> 2) & 1)) * 16 + ((kq >> 3) & 3) * 4 + (kq & 3);
}

// ---------------- weight fragment prep (once, tiny) ----------------
// All wfE frags are A-operands now (lane holds W[k=quad*8+j][m=lane&15], which
// is A[m][k] of W^T). Frag ids unchanged: We1e=0..3 (kt*2+mt), We2=4..11 (mt),
// Wn1b=12..27 (kt*4+mt), Wn2=28..43 (kt*8+mt). Rows of We2/Wn1b/Wn2 are
// permuted by hperm; We1e rows are physical (ef input) - no perm.
// wfN frag ids: combined 128x128 B = [We1[0:128] | We1[128:256] | Wn1[0:128]] -> kt*8+nt.
__global__ __launch_bounds__(256) void wprep(
    const float* __restrict__ We1, const float* __restrict__ We2,
    const float* __restrict__ Wn1, const float* __restrict__ Wn2,
    short8* __restrict__ wfE, short8* __restrict__ wfN)
{
    const int g = blockIdx.x * 256 + threadIdx.x;   // 0..4863
    const int lane = g & 63;
    const int f = g >> 6;                            // 0..75
    const int m16 = lane & 15, quad = lane >> 4;
    short v[8];
    if (f < 44) {
        #pragma unroll
        for (int j = 0; j < 8; ++j) {
            const int kq = quad * 8 + j;
            float s;
            if (f < 4) {
                const int kt = f >> 1, mt = f & 1;
                s = We1[(size_t)(2 * ND + kt * 32 + kq) * H1 + mt * 16 + m16];
            } else if (f < 12) {
                const int mt = f - 4;
                s = We2[(size_t)hperm(0, kq) * MD + mt * 16 + m16];
            } else if (f < 28) {
                const int ff = f - 12, kt = ff >> 2, mt = ff & 3;
                s = Wn1[(size_t)(ND + hperm(kt, kq)) * H2 + mt * 16 + m16];
            } else {
                const int ff = f - 28, kt = ff >> 3, mt = ff & 7;
                s = Wn2[(size_t)hperm(kt, kq) * MD + mt * 16 + m16];
            }
            v[j] = f2bf(s);
        }
        wfE[g] = short8{v[0], v[1], v[2], v[3], v[4], v[5], v[6], v[7]};
    } else {
        const int ff = f - 44, kt = ff >> 3, nt = ff & 7;
        const int n = nt * 16 + m16;
        #pragma unroll
        for (int j = 0; j < 8; ++j) {
            const int k = kt * 32 + quad * 8 + j;
            float s;
            if (n < 32)      s = We1[(size_t)k * H1 + n];
            else if (n < 64) s = We1[(size_t)(ND + k) * H1 + (n - 32)];
            else             s = Wn1[(size_t)k * H2 + (n - 64)];
            v[j] = f2bf(s);
        }
        wfN[(size_t)(f - 44) * 64 + lane] = short8{v[0], v[1], v[2], v[3], v[4], v[5], v[6], v[7]};
    }
}

// ---------------- CSR: histogram + within-segment position -----------------
__global__ __launch_bounds__(256) void hist_pos(const int* __restrict__ eidx,
                                                int* __restrict__ counts,
                                                int* __restrict__ pos) {
    const int e = blockIdx.x * 256 + threadIdx.x;
    if (e < N_EDGES) pos[e] = atomicAdd(&counts[eidx[N_EDGES + e]], 1);
}

__global__ __launch_bounds__(1024) void scan_kernel(const int* __restrict__ counts,
                                                    int* __restrict__ offsets) {
    constexpr int T = 1024;
    constexpr int CHUNK = 52;                 // 13 int4 per thread, padded buffer
    const int tid = threadIdx.x;
    const int base = tid * CHUNK;
    int4 v[13];
    int s = 0;
    const int4* pc = (const int4*)(counts + base);
    #pragma unroll
    for (int i = 0; i < 13; ++i) {
        v[i] = pc[i];
        s += v[i].x + v[i].y + v[i].z + v[i].w;
    }
    __shared__ int sm[T];
    sm[tid] = s;
    __syncthreads();
    for (int off = 1; off < T; off <<= 1) {
        const int t = (tid >= off) ? sm[tid - off] : 0;
        __syncthreads();
        sm[tid] += t;
        __syncthreads();
    }
    int run = sm[tid] - s;
    #pragma unroll
    for (int i = 0; i < 13; ++i) {
        const int idx = base + i * 4;
        if (idx     <= N_NODES) offsets[idx]     = run;  run += v[i].x;
        if (idx + 1 <= N_NODES) offsets[idx + 1] = run;  run += v[i].y;
        if (idx + 2 <= N_NODES) offsets[idx + 2] = run;  run += v[i].z;
        if (idx + 3 <= N_NODES) offsets[idx + 3] = run;  run += v[i].w;
    }
}

// ---------------- node precompute as MFMA GEMM: pre = nf @ [B128x128] -------
__global__ __launch_bounds__(256) void node_pre_mfma(
    const float* __restrict__ nf, const short8* __restrict__ wfN,
    unsigned short* __restrict__ pre)
{
    __shared__ short ost[4][2048];   // per-wave 16x128 out stage
    const int tid = threadIdx.x;
    const int w = tid >> 6, lane = tid & 63;
    const int m16 = lane & 15, quad = lane >> 4;
    const int n0 = blockIdx.x * 64 + w * 16;

    short8 a[4];
    #pragma unroll
    for (int kt = 0; kt < 4; ++kt) {
        const int node = min(n0 + m16, N_NODES - 1);
        const float* pn = nf + (size_t)node * ND + kt * 32 + quad * 8;
        const float4 f0 = *(const float4*)pn;
        const float4 f1 = *(const float4*)(pn + 4);
        a[kt] = pack8(pkbf(f0.x, f0.y), pkbf(f0.z, f0.w),
                      pkbf(f1.x, f1.y), pkbf(f1.z, f1.w));
    }
    f32x4 acc[8];
    #pragma unroll
    for (int nt = 0; nt < 8; ++nt) acc[nt] = f32x4{0.f, 0.f, 0.f, 0.f};
    #pragma unroll
    for (int kt = 0; kt < 4; ++kt) {
        #pragma unroll
        for (int nt = 0; nt < 8; ++nt)
            acc[nt] = MFMA16(a[kt], wfN[(size_t)(kt * 8 + nt) * 64 + lane], acc[nt]);
    }
    short* o = &ost[w][0];
    #pragma unroll
    for (int nt = 0; nt < 8; ++nt)
        #pragma unroll
        for (int r = 0; r < 4; ++r)
            o[(quad * 4 + r) * 128 + nt * 16 + m16] = f2bf(acc[nt][r]);  // no relu
    asm volatile("s_waitcnt lgkmcnt(0)" ::: "memory");
    #pragma unroll
    for (int i = 0; i < 4; ++i) {
        const int row = i * 4 + quad;
        const int node = n0 + row;
        if (node < N_NODES) {
            const uint4 v = ((const uint4*)(o + row * 128))[m16];
            *((uint4*)(pre + (size_t)node * 128) + m16) = v;
        }
    }
}

// ---------------- fused 4-layer edge MLP, swapped-operand MFMA --------------
// 64 edges/block, 4 independent waves x 16 edges. Weights are A-operands,
// activations are B-operands: layer outputs chain lane-locally (hperm folded
// into weights), so L1->L2->L3->L4 needs NO LDS and NO shuffles - just
// relu+v_cvt_pk_bf16_f32 packs. LDS only for gather staging (l1init/a3) and
// the final msgs coalescing stage (ost aliases the dead gather buffers).
// Per-wave scratch 4608B: l1init 16x144B @0, a3 16x144B @2304, ost 16x272B @0.
__global__ __launch_bounds__(256, 5) void edge_mfma(
    const float* __restrict__ ef, const int* __restrict__ eidx,
    const unsigned short* __restrict__ pre,
    const int* __restrict__ pos, const int* __restrict__ offsets,
    const short8* __restrict__ wfE,
    const float* __restrict__ be1, const float* __restrict__ be2,
    const float* __restrict__ bn1, const float* __restrict__ bn2,
    unsigned short* __restrict__ msgs)
{
    constexpr int TE = 64;
    __shared__ __align__(16) char sws[4][4608];
    __shared__ int slotlds[TE];

    const int tid = threadIdx.x;
    const int e0 = blockIdx.x * TE;
    const int w = tid >> 6, lane = tid & 63;
    const int m16 = lane & 15, q = lane >> 4;
    const int er0 = w * 16;
    char* swsb = &sws[w][0];

    // ---- front-load ef global loads (latency hides under gather) ----
    float4 efv0, efv1, efv2, efv3;
    {
        const float* pe = ef + (size_t)(e0 + er0 + m16) * ED + q * 8;
        efv0 = *(const float4*)pe;
        efv1 = *(const float4*)(pe + 4);
        efv2 = *(const float4*)(pe + 32);
        efv3 = *(const float4*)(pe + 36);
    }

    // ---- uniform gather: 4 lanes per edge (wave-local rows) ----
    {
        const int et = tid >> 2, p = tid & 3;   // et in [16w, 16w+16)
        const int e = e0 + et;
        const int src = eidx[e];
        const int dst = eidx[N_EDGES + e];
        const uint4* pa = (const uint4*)(pre + (size_t)src * 128);
        const uint4* pd = (const uint4*)(pre + (size_t)dst * 128);
        const uint4 ua = pa[p];                 // a1 slice (h1 = p*8..p*8+7)
        const uint4 ud = pd[4 + p];             // a2 slice
        const uint4 s0 = pd[8 + 2 * p];         // a3 slices (h3 = p*16..p*16+15)
        const uint4 s1 = pd[9 + 2 * p];
        const float4 b0 = ((const float4*)be1)[2 * p];
        const float4 b1 = ((const float4*)be1)[2 * p + 1];
        float4 r0, r1;
        r0.x = bflo(ua.x) + bflo(ud.x) + b0.x;
        r0.y = bfhi(ua.x) + bfhi(ud.x) + b0.y;
        r0.z = bflo(ua.y) + bflo(ud.y) + b0.z;
        r0.w = bfhi(ua.y) + bfhi(ud.y) + b0.w;
        r1.x = bflo(ua.z) + bflo(ud.z) + b1.x;
        r1.y = bfhi(ua.z) + bfhi(ud.z) + b1.y;
        r1.z = bflo(ua.w) + bflo(ud.w) + b1.z;
        r1.w = bfhi(ua.w) + bfhi(ud.w) + b1.w;
        char* wb = &sws[et >> 4][0] + (et & 15) * 144;
        *(float4*)(wb + p * 32) = r0;
        *(float4*)(wb + p * 32 + 16) = r1;
        char* wb2 = &sws[et >> 4][2304] + (et & 15) * 144;
        *(uint4*)(wb2 + p * 32) = s0;
        *(uint4*)(wb2 + p * 32 + 16) = s1;
        if (p == 3) slotlds[et] = offsets[dst] + pos[e];
    }
    // wave-local LDS handoff (all writes by this wave's lanes)
    asm volatile("s_waitcnt lgkmcnt(0)" ::: "memory");

    const short8 aef0 = pack8(pkbf(efv0.x, efv0.y), pkbf(efv0.z, efv0.w),
                              pkbf(efv1.x, efv1.y), pkbf(efv1.z, efv1.w));
    const short8 aef1 = pack8(pkbf(efv2.x, efv2.y), pkbf(efv2.z, efv2.w),
                              pkbf(efv3.x, efv3.y), pkbf(efv3.z, efv3.w));

    // ---- L1: C[h1=mt*16+q*4+r][edge=m16] = l1init + We1e^T x ef ----
    f32x4 acc1[2];
    #pragma unroll
    for (int mt = 0; mt < 2; ++mt)
        acc1[mt] = *(const f32x4*)(swsb + m16 * 144 + mt * 64 + q * 16);
    #pragma unroll
    for (int mt = 0; mt < 2; ++mt) {
        acc1[mt] = MFMA16(wfE[(size_t)(0 + mt) * 64 + lane], aef0, acc1[mt]);
        acc1[mt] = MFMA16(wfE[(size_t)(2 + mt) * 64 + lane], aef1, acc1[mt]);
    }

    // lane-local handoff: relu + pack into L2's B operand (hperm in weights)
    const short8 b2 = pack8(prelu(acc1[0][0], acc1[0][1]), prelu(acc1[0][2], acc1[0][3]),
                            prelu(acc1[1][0], acc1[1][1]), prelu(acc1[1][2], acc1[1][3]));

    // ---- L2: msg(128) = relu(We2^T x h + be2) ----
    f32x4 acc2[8];
    #pragma unroll
    for (int mt = 0; mt < 8; ++mt) {
        const float4 bb = *(const float4*)(be2 + mt * 16 + q * 4);
        acc2[mt] = f32x4{bb.x, bb.y, bb.z, bb.w};
        acc2[mt] = MFMA16(wfE[(size_t)(4 + mt) * 64 + lane], b2, acc2[mt]);
    }
    short8 b3[4];
    #pragma unroll
    for (int kt = 0; kt < 4; ++kt)
        b3[kt] = pack8(prelu(acc2[2 * kt][0], acc2[2 * kt][1]),
                       prelu(acc2[2 * kt][2], acc2[2 * kt][3]),
                       prelu(acc2[2 * kt + 1][0], acc2[2 * kt + 1][1]),
                       prelu(acc2[2 * kt + 1][2], acc2[2 * kt + 1][3]));

    // ---- L3: h2(64) = relu(a3 + bn1 + Wn1b^T x msg) ----
    f32x4 acc3[4];
    #pragma unroll
    for (int mt = 0; mt < 4; ++mt) {
        const float4 bb = *(const float4*)(bn1 + mt * 16 + q * 4);
        const uint2 ua = *(const uint2*)(swsb + 2304 + m16 * 144 + mt * 32 + q * 8);
        acc3[mt] = f32x4{bb.x + bflo(ua.x), bb.y + bfhi(ua.x),
                         bb.z + bflo(ua.y), bb.w + bfhi(ua.y)};
    }
    #pragma unroll
    for (int kt = 0; kt < 4; ++kt) {
        #pragma unroll
        for (int mt = 0; mt < 4; ++mt)
            acc3[mt] = MFMA16(wfE[(size_t)(12 + kt * 4 + mt) * 64 + lane], b3[kt], acc3[mt]);
    }
    short8 b4[2];
    #pragma unroll
    for (int kt = 0; kt < 2; ++kt)
        b4[kt] = pack8(prelu(acc3[2 * kt][0], acc3[2 * kt][1]),
                       prelu(acc3[2 * kt][2], acc3[2 * kt][3]),
                       prelu(acc3[2 * kt + 1][0], acc3[2 * kt + 1][1]),
                       prelu(acc3[2 * kt + 1][2], acc3[2 * kt + 1][3]));

    // ---- L4: out(128) = relu(Wn2^T x h2 + bn2) ----
    f32x4 acc4[8];
    #pragma unroll
    for (int mt = 0; mt < 8; ++mt) {
        const float4 bb = *(const float4*)(bn2 + mt * 16 + q * 4);
        acc4[mt] = f32x4{bb.x, bb.y, bb.z, bb.w};
    }
    #pragma unroll
    for (int kt = 0; kt < 2; ++kt) {
        #pragma unroll
        for (int mt = 0; mt < 8; ++mt)
            acc4[mt] = MFMA16(wfE[(size_t)(28 + kt * 8 + mt) * 64 + lane], b4[kt], acc4[mt]);
    }

    // ---- stage to ost (aliases dead l1init/a3; row=edge m16, stride 272B) ----
    #pragma unroll
    for (int mt = 0; mt < 8; ++mt) {
        uint2 wv;
        wv.x = prelu(acc4[mt][0], acc4[mt][1]);
        wv.y = prelu(acc4[mt][2], acc4[mt][3]);
        *(uint2*)(swsb + m16 * 272 + mt * 32 + q * 8) = wv;
    }
    asm volatile("s_waitcnt lgkmcnt(0)" ::: "memory");

    // ---- coalesced row store to msgs[slot] (quarter-wave per 256B row) ----
    #pragma unroll
    for (int i = 0; i < 4; ++i) {
        const int row = i * 4 + q;
        const int sl = slotlds[er0 + row];
        const uint4 v = *(const uint4*)(swsb + row * 272 + m16 * 16);
        *((uint4*)(msgs + (size_t)sl * 128) + m16) = v;
    }
}

// ---------------- Phase B: per-node streaming sum (msgs CSR-sorted) ---------
// 16 lanes per node, uint4 (16B) loads: 256B/row/iter, 2x unrolled.
__global__ __launch_bounds__(256) void gather2(
    const float* __restrict__ nf,
    const uint4* __restrict__ msgs4,
    const int* __restrict__ offsets,
    float* __restrict__ out)
{
    const int node = blockIdx.x * 16 + (threadIdx.x >> 4);
    const int m16 = threadIdx.x & 15;

    const float4* pn = (const float4*)(nf + (size_t)node * ND) + m16 * 2;
    const float4 n0 = pn[0];
    const float4 n1 = pn[1];

    const int beg = offsets[node];
    const int end = offsets[node + 1];

    float4 s0 = float4{0.f, 0.f, 0.f, 0.f};
    float4 s1 = float4{0.f, 0.f, 0.f, 0.f};
    const uint4* p = msgs4 + (size_t)beg * 16 + m16;   // 16 uint4 per 256B msg row
    int i = beg;
    for (; i + 1 < end; i += 2, p += 32) {
        const uint4 u0 = p[0];
        const uint4 u1 = p[16];
        s0.x += bflo(u0.x); s0.y += bfhi(u0.x);
        s0.z += bflo(u0.y); s0.w += bfhi(u0.y);
        s1.x += bflo(u0.z); s1.y += bfhi(u0.z);
        s1.z += bflo(u0.w); s1.w += bfhi(u0.w);
        s0.x += bflo(u1.x); s0.y += bfhi(u1.x);
        s0.z += bflo(u1.y); s0.w += bfhi(u1.y);
        s1.x += bflo(u1.z); s1.y += bfhi(u1.z);
        s1.z += bflo(u1.w); s1.w += bfhi(u1.w);
    }
    if (i < end) {
        const uint4 u = p[0];
        s0.x += bflo(u.x); s0.y += bfhi(u.x);
        s0.z += bflo(u.y); s0.w += bfhi(u.y);
        s1.x += bflo(u.z); s1.y += bfhi(u.z);
        s1.z += bflo(u.w); s1.w += bfhi(u.w);
    }
    s0.x += n0.x; s0.y += n0.y; s0.z += n0.z; s0.w += n0.w;
    s1.x += n1.x; s1.y += n1.y; s1.z += n1.z; s1.w += n1.w;

    float4* po = (float4*)(out + (size_t)node * ND) + m16 * 2;
    po[0] = s0;
    po[1] = s1;
}

extern "C" void kernel_launch(void* const* d_in, const int* in_sizes, int n_in,
                              void* d_out, int out_size, void* d_ws, size_t ws_size,
                              hipStream_t stream) {
    const float* nf  = (const float*)d_in[0];
    const float* ef  = (const float*)d_in[1];
    const int*  eidx = (const int*)d_in[2];
    const float* We1 = (const float*)d_in[3];
    const float* be1 = (const float*)d_in[4];
    const float* We2 = (const float*)d_in[5];
    const float* be2 = (const float*)d_in[6];
    const float* Wn1 = (const float*)d_in[7];
    const float* bn1 = (const float*)d_in[8];
    const float* Wn2 = (const float*)d_in[9];
    const float* bn2 = (const float*)d_in[10];
    float* out = (float*)d_out;

    char* ws = (char*)d_ws;
    unsigned short* msgs = (unsigned short*)(ws + WS_MSGS);
    unsigned short* pre  = (unsigned short*)(ws + WS_PRE);
    int* pos             = (int*)(ws + WS_POS);
    int* counts          = (int*)(ws + WS_COUNTS);
    int* offsets         = (int*)(ws + WS_OFFSETS);
    short8* wfE          = (short8*)(ws + WS_WFE);
    short8* wfN          = (short8*)(ws + WS_WFN);
    (void)ws_size; (void)WS_END;

    hipMemsetAsync(counts, 0, (size_t)COUNTS_PAD * 4, stream);
    wprep<<<19, 256, 0, stream>>>(We1, We2, Wn1, Wn2, wfE, wfN);
    hist_pos<<<(N_EDGES + 255) / 256, 256, 0, stream>>>(eidx, counts, pos);
    scan_kernel<<<1, 1024, 0, stream>>>(counts, offsets);
    node_pre_mfma<<<(N_NODES + 63) / 64, 256, 0, stream>>>(nf, wfN, pre);
    edge_mfma<<<N_EDGES / 64, 256, 0, stream>>>(
        ef, eidx, pre, pos, offsets, wfE, be1, be2, bn1, bn2, msgs);
    gather2<<<N_NODES / 16, 256, 0, stream>>>(nf, (const uint4*)msgs, offsets, out);
}

// Round 3
// 422.555 us; speedup vs baseline: 1.2680x; 1.0866x over previous
//
#include <hip/hip_runtime.h>
#include <hip/hip_bf16.h>

// Problem constants (from reference)
constexpr int N_NODES = 50000;
constexpr int N_EDGES = 600000;
constexpr int ND = 128;   // NODE_DIM
constexpr int ED = 64;    // EDGE_DIM
constexpr int MD = 128;   // MSG_DIM
constexpr int H1 = 32;    // edge MLP hidden
constexpr int H2 = 64;    // node MLP hidden

typedef __attribute__((ext_vector_type(8))) short short8;   // 8 bf16 (4 VGPRs)
typedef __attribute__((ext_vector_type(4))) float f32x4;    // MFMA acc
typedef __attribute__((ext_vector_type(4))) unsigned int uint32x4;

#define MFMA16(a, b, c) __builtin_amdgcn_mfma_f32_16x16x32_bf16((a), (b), (c), 0, 0, 0)

// ---------------- workspace layout (bytes) ----------------
constexpr int COUNTS_PAD = 53248;   // 1024*52 (scan CHUNK=52, int4 loads)
constexpr size_t WS_MSGS    = 0;                                        // E*128 bf16
constexpr size_t WS_PRE     = WS_MSGS + (size_t)N_EDGES * MD * 2;       // N*128 bf16 (a1|a2|a3)
constexpr size_t WS_POS     = WS_PRE + (size_t)N_NODES * 128 * 2;       // E int
constexpr size_t WS_COUNTS  = WS_POS + (size_t)N_EDGES * 4;             // COUNTS_PAD int
constexpr size_t WS_OFFSETS = WS_COUNTS + (size_t)COUNTS_PAD * 4;       // N+1 int
constexpr size_t WS_WFE     = ((WS_OFFSETS + (size_t)(N_NODES + 1) * 4 + 15) / 16) * 16;
constexpr size_t WS_WFN     = WS_WFE + (size_t)44 * 64 * 16;            // 44 edge frags
constexpr size_t WS_END     = WS_WFN + (size_t)32 * 64 * 16;            // 32 node frags

__device__ inline float bflo(unsigned u) { return __uint_as_float(u << 16); }
__device__ inline float bfhi(unsigned u) { return __uint_as_float(u & 0xffff0000u); }
__device__ inline short f2bf(float f) {
    __hip_bfloat16 h = __float2bfloat16(f);
    return *reinterpret_cast<short*>(&h);
}
// packed f32 pair -> bf16 pair (1 instr)
__device__ inline unsigned pkbf(float a, float b) {
    unsigned r;
    asm("v_cvt_pk_bf16_f32 %0, %1, %2" : "=v"(r) : "v"(a), "v"(b));
    return r;
}
__device__ inline unsigned prelu(float a, float b) {
    return pkbf(fmaxf(a, 0.0f), fmaxf(b, 0.0f));
}
__device__ inline short8 pack8(unsigned w0, unsigned w1, unsigned w2, unsigned w3) {
    uint32x4 t{w0, w1, w2, w3};
    return __builtin_bit_cast(short8, t);
}

// Hidden-dim relabeling for swapped-operand layer chaining:
// layer i's output at lane(q,m16) reg (mt,r) carries h = mt*16 + q*4 + r,
// which slots into next layer's B-operand k = kt*32 + q*8 + j with
// mt = kt*2 + (j>>2), r = j&3. Fold h(k) into the weight row order here.
__device__ inline int hperm(int kt, int kq) {   // kq = quad*8+j in [0,32)
    return (kt * 2 + ((kq >> 2) & 1)) * 16 + ((kq >> 3) & 3) * 4 + (kq & 3);
}

// ---------------- weight fragment prep (once, tiny) ----------------
// All wfE frags are A-operands (lane holds W[k=quad*8+j][m=lane&15] = A[m][k]
// of W^T). Frag ids: We1e=0..3 (kt*2+mt), We2=4..11 (mt), Wn1b=12..27
// (kt*4+mt), Wn2=28..43 (kt*8+mt). We2/Wn1b/Wn2 rows permuted by hperm.
// wfN frag ids: combined 128x128 B = [We1[0:128] | We1[128:256] | Wn1[0:128]] -> kt*8+nt.
__global__ __launch_bounds__(256) void wprep(
    const float* __restrict__ We1, const float* __restrict__ We2,
    const float* __restrict__ Wn1, const float* __restrict__ Wn2,
    short8* __restrict__ wfE, short8* __restrict__ wfN)
{
    const int g = blockIdx.x * 256 + threadIdx.x;   // 0..4863
    const int lane = g & 63;
    const int f = g >> 6;                            // 0..75
    const int m16 = lane & 15, quad = lane >> 4;
    short v[8];
    if (f < 44) {
        #pragma unroll
        for (int j = 0; j < 8; ++j) {
            const int kq = quad * 8 + j;
            float s;
            if (f < 4) {
                const int kt = f >> 1, mt = f & 1;
                s = We1[(size_t)(2 * ND + kt * 32 + kq) * H1 + mt * 16 + m16];
            } else if (f < 12) {
                const int mt = f - 4;
                s = We2[(size_t)hperm(0, kq) * MD + mt * 16 + m16];
            } else if (f < 28) {
                const int ff = f - 12, kt = ff >> 2, mt = ff & 3;
                s = Wn1[(size_t)(ND + hperm(kt, kq)) * H2 + mt * 16 + m16];
            } else {
                const int ff = f - 28, kt = ff >> 3, mt = ff & 7;
                s = Wn2[(size_t)hperm(kt, kq) * MD + mt * 16 + m16];
            }
            v[j] = f2bf(s);
        }
        wfE[g] = short8{v[0], v[1], v[2], v[3], v[4], v[5], v[6], v[7]};
    } else {
        const int ff = f - 44, kt = ff >> 3, nt = ff & 7;
        const int n = nt * 16 + m16;
        #pragma unroll
        for (int j = 0; j < 8; ++j) {
            const int k = kt * 32 + quad * 8 + j;
            float s;
            if (n < 32)      s = We1[(size_t)k * H1 + n];
            else if (n < 64) s = We1[(size_t)(ND + k) * H1 + (n - 32)];
            else             s = Wn1[(size_t)k * H2 + (n - 64)];
            v[j] = f2bf(s);
        }
        wfN[(size_t)(f - 44) * 64 + lane] = short8{v[0], v[1], v[2], v[3], v[4], v[5], v[6], v[7]};
    }
}

// ---------------- CSR: histogram + within-segment position -----------------
__global__ __launch_bounds__(256) void hist_pos(const int* __restrict__ eidx,
                                                int* __restrict__ counts,
                                                int* __restrict__ pos) {
    const int e = blockIdx.x * 256 + threadIdx.x;
    if (e < N_EDGES) pos[e] = atomicAdd(&counts[eidx[N_EDGES + e]], 1);
}

__global__ __launch_bounds__(1024) void scan_kernel(const int* __restrict__ counts,
                                                    int* __restrict__ offsets) {
    constexpr int T = 1024;
    const int tid = threadIdx.x;
    const int base = tid * 52;
    int4 v[13];
    int s = 0;
    const int4* pc = (const int4*)(counts + base);
    #pragma unroll
    for (int i = 0; i < 13; ++i) {
        v[i] = pc[i];
        s += v[i].x + v[i].y + v[i].z + v[i].w;
    }
    __shared__ int sm[T];
    sm[tid] = s;
    __syncthreads();
    for (int off = 1; off < T; off <<= 1) {
        const int t = (tid >= off) ? sm[tid - off] : 0;
        __syncthreads();
        sm[tid] += t;
        __syncthreads();
    }
    int run = sm[tid] - s;
    #pragma unroll
    for (int i = 0; i < 13; ++i) {
        const int idx = base + i * 4;
        if (idx     <= N_NODES) offsets[idx]     = run;  run += v[i].x;
        if (idx + 1 <= N_NODES) offsets[idx + 1] = run;  run += v[i].y;
        if (idx + 2 <= N_NODES) offsets[idx + 2] = run;  run += v[i].z;
        if (idx + 3 <= N_NODES) offsets[idx + 3] = run;  run += v[i].w;
    }
}

// ---------------- node precompute as MFMA GEMM: pre = nf @ [B128x128] -------
__global__ __launch_bounds__(256) void node_pre_mfma(
    const float* __restrict__ nf, const short8* __restrict__ wfN,
    unsigned short* __restrict__ pre)
{
    __shared__ short ost[4][2048];   // per-wave 16x128 out stage
    const int tid = threadIdx.x;
    const int w = tid >> 6, lane = tid & 63;
    const int m16 = lane & 15, quad = lane >> 4;
    const int n0 = blockIdx.x * 64 + w * 16;

    short8 a[4];
    #pragma unroll
    for (int kt = 0; kt < 4; ++kt) {
        const int node = min(n0 + m16, N_NODES - 1);
        const float* pn = nf + (size_t)node * ND + kt * 32 + quad * 8;
        const float4 f0 = *(const float4*)pn;
        const float4 f1 = *(const float4*)(pn + 4);
        a[kt] = pack8(pkbf(f0.x, f0.y), pkbf(f0.z, f0.w),
                      pkbf(f1.x, f1.y), pkbf(f1.z, f1.w));
    }
    f32x4 acc[8];
    #pragma unroll
    for (int nt = 0; nt < 8; ++nt) acc[nt] = f32x4{0.f, 0.f, 0.f, 0.f};
    #pragma unroll
    for (int kt = 0; kt < 4; ++kt) {
        #pragma unroll
        for (int nt = 0; nt < 8; ++nt)
            acc[nt] = MFMA16(a[kt], wfN[(size_t)(kt * 8 + nt) * 64 + lane], acc[nt]);
    }
    short* o = &ost[w][0];
    #pragma unroll
    for (int nt = 0; nt < 8; ++nt)
        #pragma unroll
        for (int r = 0; r < 4; ++r)
            o[(quad * 4 + r) * 128 + nt * 16 + m16] = f2bf(acc[nt][r]);  // no relu
    asm volatile("s_waitcnt lgkmcnt(0)" ::: "memory");
    #pragma unroll
    for (int i = 0; i < 4; ++i) {
        const int row = i * 4 + quad;
        const int node = n0 + row;
        if (node < N_NODES) {
            const uint4 v = ((const uint4*)(o + row * 128))[m16];
            *((uint4*)(pre + (size_t)node * 128) + m16) = v;
        }
    }
}

// ---------------- fused 4-layer edge MLP, swapped-operand, 2 tiles/wave -----
// 128 edges/block, 4 independent waves x 2 tiles x 16 edges. Each wfE weight
// fragment is loaded ONCE from L2 and feeds TWO independent MFMA chains
// (tiles A,B) - halves weight-load count per edge and doubles ILP so L2
// latency hides under the sibling tile's work. Layer outputs chain
// lane-locally (hperm folded into weights): no LDS between layers.
// Per-wave LDS 9216B: per tile 4608B = l1init 16x144 @0 (a3 @2304), final
// out-stage 16x272 aliases it.
__global__ __launch_bounds__(256, 4) void edge_mfma(
    const float* __restrict__ ef, const int* __restrict__ eidx,
    const unsigned short* __restrict__ pre,
    const int* __restrict__ pos, const int* __restrict__ offsets,
    const short8* __restrict__ wfE,
    const float* __restrict__ be1, const float* __restrict__ be2,
    const float* __restrict__ bn1, const float* __restrict__ bn2,
    unsigned short* __restrict__ msgs)
{
    constexpr int TE = 128;
    __shared__ __align__(16) char sws[4][9216];
    __shared__ int slotlds[TE];

    const int tid = threadIdx.x;
    const int e0 = blockIdx.x * TE;
    const bool hasB = (e0 + 64) < N_EDGES;          // block-uniform (last block only A)
    const int w = tid >> 6, lane = tid & 63;
    const int m16 = lane & 15, q = lane >> 4;
    const int er0 = w * 16;
    char* swsb = &sws[w][0];

    // ---- front-load ef global loads for both tiles ----
    float4 efv[2][4];
    {
        const float* pe = ef + (size_t)(e0 + er0 + m16) * ED + q * 8;
        efv[0][0] = *(const float4*)pe;
        efv[0][1] = *(const float4*)(pe + 4);
        efv[0][2] = *(const float4*)(pe + 32);
        efv[0][3] = *(const float4*)(pe + 36);
        if (hasB) {
            const float* pe2 = pe + (size_t)64 * ED;
            efv[1][0] = *(const float4*)pe2;
            efv[1][1] = *(const float4*)(pe2 + 4);
            efv[1][2] = *(const float4*)(pe2 + 32);
            efv[1][3] = *(const float4*)(pe2 + 36);
        }
    }

    // ---- gather: 4 lanes/edge, both passes' loads issued before LDS writes ----
    {
        const int et = tid >> 2, p4 = tid & 3;      // et in [16w,16w+16)
        const int eA = e0 + et;
        const int srcA = eidx[eA];
        const int dstA = eidx[N_EDGES + eA];
        const uint4* paA = (const uint4*)(pre + (size_t)srcA * 128);
        const uint4* pdA = (const uint4*)(pre + (size_t)dstA * 128);
        const uint4 uaA = paA[p4];
        const uint4 udA = pdA[4 + p4];
        const uint4 s0A = pdA[8 + 2 * p4];
        const uint4 s1A = pdA[9 + 2 * p4];
        const int slA = offsets[dstA] + pos[eA];

        uint4 uaB, udB, s0B, s1B;
        int slB = 0;
        if (hasB) {
            const int eB = eA + 64;
            const int srcB = eidx[eB];
            const int dstB = eidx[N_EDGES + eB];
            const uint4* paB = (const uint4*)(pre + (size_t)srcB * 128);
            const uint4* pdB = (const uint4*)(pre + (size_t)dstB * 128);
            uaB = paB[p4];
            udB = pdB[4 + p4];
            s0B = pdB[8 + 2 * p4];
            s1B = pdB[9 + 2 * p4];
            slB = offsets[dstB] + pos[eB];
        }
        const float4 b0 = ((const float4*)be1)[2 * p4];
        const float4 b1 = ((const float4*)be1)[2 * p4 + 1];

        char* wbase = &sws[et >> 4][0] + (et & 15) * 144;
        {
            float4 r0, r1;
            r0.x = bflo(uaA.x) + bflo(udA.x) + b0.x;
            r0.y = bfhi(uaA.x) + bfhi(udA.x) + b0.y;
            r0.z = bflo(uaA.y) + bflo(udA.y) + b0.z;
            r0.w = bfhi(uaA.y) + bfhi(udA.y) + b0.w;
            r1.x = bflo(uaA.z) + bflo(udA.z) + b1.x;
            r1.y = bfhi(uaA.z) + bfhi(udA.z) + b1.y;
            r1.z = bflo(uaA.w) + bflo(udA.w) + b1.z;
            r1.w = bfhi(uaA.w) + bfhi(udA.w) + b1.w;
            *(float4*)(wbase + p4 * 32) = r0;
            *(float4*)(wbase + p4 * 32 + 16) = r1;
            *(uint4*)(wbase + 2304 + p4 * 32) = s0A;
            *(uint4*)(wbase + 2304 + p4 * 32 + 16) = s1A;
            if (p4 == 3) slotlds[et] = slA;
        }
        if (hasB) {
            float4 r0, r1;
            r0.x = bflo(uaB.x) + bflo(udB.x) + b0.x;
            r0.y = bfhi(uaB.x) + bfhi(udB.x) + b0.y;
            r0.z = bflo(uaB.y) + bflo(udB.y) + b0.z;
            r0.w = bfhi(uaB.y) + bfhi(udB.y) + b0.w;
            r1.x = bflo(uaB.z) + bflo(udB.z) + b1.x;
            r1.y = bfhi(uaB.z) + bfhi(udB.z) + b1.y;
            r1.z = bflo(uaB.w) + bflo(udB.w) + b1.z;
            r1.w = bfhi(uaB.w) + bfhi(udB.w) + b1.w;
            *(float4*)(wbase + 4608 + p4 * 32) = r0;
            *(float4*)(wbase + 4608 + p4 * 32 + 16) = r1;
            *(uint4*)(wbase + 4608 + 2304 + p4 * 32) = s0B;
            *(uint4*)(wbase + 4608 + 2304 + p4 * 32 + 16) = s1B;
            if (p4 == 3) slotlds[64 + et] = slB;
        }
    }
    // wave-local LDS handoff (all writes by this wave's lanes)
    asm volatile("s_waitcnt lgkmcnt(0)" ::: "memory");

    short8 aef[2][2];
    #pragma unroll
    for (int t = 0; t < 2; ++t) {
        aef[t][0] = pack8(pkbf(efv[t][0].x, efv[t][0].y), pkbf(efv[t][0].z, efv[t][0].w),
                          pkbf(efv[t][1].x, efv[t][1].y), pkbf(efv[t][1].z, efv[t][1].w));
        aef[t][1] = pack8(pkbf(efv[t][2].x, efv[t][2].y), pkbf(efv[t][2].z, efv[t][2].w),
                          pkbf(efv[t][3].x, efv[t][3].y), pkbf(efv[t][3].z, efv[t][3].w));
    }

    // ---- L1: C[h1][edge] = l1init + We1e^T x ef (both tiles share frags) ----
    f32x4 acc1[2][2];
    #pragma unroll
    for (int t = 0; t < 2; ++t)
        #pragma unroll
        for (int mt = 0; mt < 2; ++mt)
            acc1[t][mt] = *(const f32x4*)(swsb + t * 4608 + m16 * 144 + mt * 64 + q * 16);
    #pragma unroll
    for (int kt = 0; kt < 2; ++kt)
        #pragma unroll
        for (int mt = 0; mt < 2; ++mt) {
            const short8 wf = wfE[(size_t)(kt * 2 + mt) * 64 + lane];
            acc1[0][mt] = MFMA16(wf, aef[0][kt], acc1[0][mt]);
            acc1[1][mt] = MFMA16(wf, aef[1][kt], acc1[1][mt]);
        }

    short8 b2[2];
    #pragma unroll
    for (int t = 0; t < 2; ++t)
        b2[t] = pack8(prelu(acc1[t][0][0], acc1[t][0][1]), prelu(acc1[t][0][2], acc1[t][0][3]),
                      prelu(acc1[t][1][0], acc1[t][1][1]), prelu(acc1[t][1][2], acc1[t][1][3]));

    // ---- L2: msg(128) = relu(We2^T x h + be2) ----
    f32x4 acc2[2][8];
    #pragma unroll
    for (int mt = 0; mt < 8; ++mt) {
        const float4 bb = *(const float4*)(be2 + mt * 16 + q * 4);
        const short8 wf = wfE[(size_t)(4 + mt) * 64 + lane];
        acc2[0][mt] = f32x4{bb.x, bb.y, bb.z, bb.w};
        acc2[1][mt] = acc2[0][mt];
        acc2[0][mt] = MFMA16(wf, b2[0], acc2[0][mt]);
        acc2[1][mt] = MFMA16(wf, b2[1], acc2[1][mt]);
    }
    short8 b3[2][4];
    #pragma unroll
    for (int t = 0; t < 2; ++t)
        #pragma unroll
        for (int kt = 0; kt < 4; ++kt)
            b3[t][kt] = pack8(prelu(acc2[t][2 * kt][0], acc2[t][2 * kt][1]),
                              prelu(acc2[t][2 * kt][2], acc2[t][2 * kt][3]),
                              prelu(acc2[t][2 * kt + 1][0], acc2[t][2 * kt + 1][1]),
                              prelu(acc2[t][2 * kt + 1][2], acc2[t][2 * kt + 1][3]));

    // ---- L3: h2(64) = relu(a3 + bn1 + Wn1b^T x msg) ----
    f32x4 acc3[2][4];
    #pragma unroll
    for (int mt = 0; mt < 4; ++mt) {
        const float4 bb = *(const float4*)(bn1 + mt * 16 + q * 4);
        #pragma unroll
        for (int t = 0; t < 2; ++t) {
            const uint2 ua = *(const uint2*)(swsb + t * 4608 + 2304 + m16 * 144 + mt * 32 + q * 8);
            acc3[t][mt] = f32x4{bb.x + bflo(ua.x), bb.y + bfhi(ua.x),
                                bb.z + bflo(ua.y), bb.w + bfhi(ua.y)};
        }
    }
    #pragma unroll
    for (int kt = 0; kt < 4; ++kt)
        #pragma unroll
        for (int mt = 0; mt < 4; ++mt) {
            const short8 wf = wfE[(size_t)(12 + kt * 4 + mt) * 64 + lane];
            acc3[0][mt] = MFMA16(wf, b3[0][kt], acc3[0][mt]);
            acc3[1][mt] = MFMA16(wf, b3[1][kt], acc3[1][mt]);
        }
    short8 b4[2][2];
    #pragma unroll
    for (int t = 0; t < 2; ++t)
        #pragma unroll
        for (int kt = 0; kt < 2; ++kt)
            b4[t][kt] = pack8(prelu(acc3[t][2 * kt][0], acc3[t][2 * kt][1]),
                              prelu(acc3[t][2 * kt][2], acc3[t][2 * kt][3]),
                              prelu(acc3[t][2 * kt + 1][0], acc3[t][2 * kt + 1][1]),
                              prelu(acc3[t][2 * kt + 1][2], acc3[t][2 * kt + 1][3]));

    // ---- L4: out(128) = relu(Wn2^T x h2 + bn2) ----
    f32x4 acc4[2][8];
    #pragma unroll
    for (int mt = 0; mt < 8; ++mt) {
        const float4 bb = *(const float4*)(bn2 + mt * 16 + q * 4);
        acc4[0][mt] = f32x4{bb.x, bb.y, bb.z, bb.w};
        acc4[1][mt] = acc4[0][mt];
    }
    #pragma unroll
    for (int kt = 0; kt < 2; ++kt)
        #pragma unroll
        for (int mt = 0; mt < 8; ++mt) {
            const short8 wf = wfE[(size_t)(28 + kt * 8 + mt) * 64 + lane];
            acc4[0][mt] = MFMA16(wf, b4[0][kt], acc4[0][mt]);
            acc4[1][mt] = MFMA16(wf, b4[1][kt], acc4[1][mt]);
        }

    // ---- stage to out-stage (aliases dead staging; row=edge m16, stride 272) ----
    #pragma unroll
    for (int t = 0; t < 2; ++t)
        #pragma unroll
        for (int mt = 0; mt < 8; ++mt) {
            uint2 wv;
            wv.x = prelu(acc4[t][mt][0], acc4[t][mt][1]);
            wv.y = prelu(acc4[t][mt][2], acc4[t][mt][3]);
            *(uint2*)(swsb + t * 4608 + m16 * 272 + mt * 32 + q * 8) = wv;
        }
    asm volatile("s_waitcnt lgkmcnt(0)" ::: "memory");

    // ---- coalesced row store to msgs[slot] (quarter-wave per 256B row) ----
    #pragma unroll
    for (int i = 0; i < 4; ++i) {
        const int row = i * 4 + q;
        const int slA = slotlds[er0 + row];
        const uint4 vA = *(const uint4*)(swsb + row * 272 + m16 * 16);
        *((uint4*)(msgs + (size_t)slA * 128) + m16) = vA;
    }
    if (hasB) {
        #pragma unroll
        for (int i = 0; i < 4; ++i) {
            const int row = i * 4 + q;
            const int slB = slotlds[64 + er0 + row];
            const uint4 vB = *(const uint4*)(swsb + 4608 + row * 272 + m16 * 16);
            *((uint4*)(msgs + (size_t)slB * 128) + m16) = vB;
        }
    }
}

// ---------------- Phase B: per-node streaming sum (msgs CSR-sorted) ---------
// 16 lanes/node, uint4 loads, 4-row unroll with dual accumulator sets (MLP).
__global__ __launch_bounds__(256) void gather2(
    const float* __restrict__ nf,
    const uint4* __restrict__ msgs4,
    const int* __restrict__ offsets,
    float* __restrict__ out)
{
    const int node = blockIdx.x * 16 + (threadIdx.x >> 4);
    const int m16 = threadIdx.x & 15;

    const float4* pn = (const float4*)(nf + (size_t)node * ND) + m16 * 2;
    const float4 n0 = pn[0];
    const float4 n1 = pn[1];

    const int beg = offsets[node];
    const int end = offsets[node + 1];

    float4 sA0{0.f, 0.f, 0.f, 0.f}, sA1{0.f, 0.f, 0.f, 0.f};
    float4 sB0{0.f, 0.f, 0.f, 0.f}, sB1{0.f, 0.f, 0.f, 0.f};
    const uint4* p = msgs4 + (size_t)beg * 16 + m16;   // 16 uint4 per 256B msg row
    int i = beg;
    for (; i + 3 < end; i += 4, p += 64) {
        const uint4 u0 = p[0];
        const uint4 u1 = p[16];
        const uint4 u2 = p[32];
        const uint4 u3 = p[48];
        sA0.x += bflo(u0.x); sA0.y += bfhi(u0.x); sA0.z += bflo(u0.y); sA0.w += bfhi(u0.y);
        sA1.x += bflo(u0.z); sA1.y += bfhi(u0.z); sA1.z += bflo(u0.w); sA1.w += bfhi(u0.w);
        sB0.x += bflo(u1.x); sB0.y += bfhi(u1.x); sB0.z += bflo(u1.y); sB0.w += bfhi(u1.y);
        sB1.x += bflo(u1.z); sB1.y += bfhi(u1.z); sB1.z += bflo(u1.w); sB1.w += bfhi(u1.w);
        sA0.x += bflo(u2.x); sA0.y += bfhi(u2.x); sA0.z += bflo(u2.y); sA0.w += bfhi(u2.y);
        sA1.x += bflo(u2.z); sA1.y += bfhi(u2.z); sA1.z += bflo(u2.w); sA1.w += bfhi(u2.w);
        sB0.x += bflo(u3.x); sB0.y += bfhi(u3.x); sB0.z += bflo(u3.y); sB0.w += bfhi(u3.y);
        sB1.x += bflo(u3.z); sB1.y += bfhi(u3.z); sB1.z += bflo(u3.w); sB1.w += bfhi(u3.w);
    }
    for (; i < end; ++i, p += 16) {
        const uint4 u = p[0];
        sA0.x += bflo(u.x); sA0.y += bfhi(u.x); sA0.z += bflo(u.y); sA0.w += bfhi(u.y);
        sA1.x += bflo(u.z); sA1.y += bfhi(u.z); sA1.z += bflo(u.w); sA1.w += bfhi(u.w);
    }
    float4 s0, s1;
    s0.x = sA0.x + sB0.x + n0.x; s0.y = sA0.y + sB0.y + n0.y;
    s0.z = sA0.z + sB0.z + n0.z; s0.w = sA0.w + sB0.w + n0.w;
    s1.x = sA1.x + sB1.x + n1.x; s1.y = sA1.y + sB1.y + n1.y;
    s1.z = sA1.z + sB1.z + n1.z; s1.w = sA1.w + sB1.w + n1.w;

    float4* po = (float4*)(out + (size_t)node * ND) + m16 * 2;
    po[0] = s0;
    po[1] = s1;
}

extern "C" void kernel_launch(void* const* d_in, const int* in_sizes, int n_in,
                              void* d_out, int out_size, void* d_ws, size_t ws_size,
                              hipStream_t stream) {
    const float* nf  = (const float*)d_in[0];
    const float* ef  = (const float*)d_in[1];
    const int*  eidx = (const int*)d_in[2];
    const float* We1 = (const float*)d_in[3];
    const float* be1 = (const float*)d_in[4];
    const float* We2 = (const float*)d_in[5];
    const float* be2 = (const float*)d_in[6];
    const float* Wn1 = (const float*)d_in[7];
    const float* bn1 = (const float*)d_in[8];
    const float* Wn2 = (const float*)d_in[9];
    const float* bn2 = (const float*)d_in[10];
    float* out = (float*)d_out;

    char* ws = (char*)d_ws;
    unsigned short* msgs = (unsigned short*)(ws + WS_MSGS);
    unsigned short* pre  = (unsigned short*)(ws + WS_PRE);
    int* pos             = (int*)(ws + WS_POS);
    int* counts          = (int*)(ws + WS_COUNTS);
    int* offsets         = (int*)(ws + WS_OFFSETS);
    short8* wfE          = (short8*)(ws + WS_WFE);
    short8* wfN          = (short8*)(ws + WS_WFN);
    (void)ws_size; (void)WS_END;

    hipMemsetAsync(counts, 0, (size_t)COUNTS_PAD * 4, stream);
    wprep<<<19, 256, 0, stream>>>(We1, We2, Wn1, Wn2, wfE, wfN);
    hist_pos<<<(N_EDGES + 255) / 256, 256, 0, stream>>>(eidx, counts, pos);
    scan_kernel<<<1, 1024, 0, stream>>>(counts, offsets);
    node_pre_mfma<<<(N_NODES + 63) / 64, 256, 0, stream>>>(nf, wfN, pre);
    edge_mfma<<<(N_EDGES + 127) / 128, 256, 0, stream>>>(
        ef, eidx, pre, pos, offsets, wfE, be1, be2, bn1, bn2, msgs);
    gather2<<<N_NODES / 16, 256, 0, stream>>>(nf, (const uint4*)msgs, offsets, out);
}